// Round 1
// baseline (675.126 us; speedup 1.0000x reference)
//
#include <hip/hip_runtime.h>
#include <stdint.h>

// PackBits: out[w] = packed sign bits of x[32w .. 32w+31].
// Bit mapping (np.packbits MSB-first + little-endian uint32 view):
//   element p -> bit q = 8*(p>>3) + 7 - (p&7)   (bit-reverse within each byte)
// Implemented as: build natural-order word (bit p = signbit), then
//   out = bswap(brev(nat))  — brev reverses bits AND bytes, bswap undoes bytes.
// Sign bit taken from the raw IEEE bit 31 (exact signbit semantics).

__global__ __launch_bounds__(256) void PackBits_61289183314094_kernel(
    const uint4* __restrict__ x4, uint32_t* __restrict__ out, int nwords) {
  int w = blockIdx.x * blockDim.x + threadIdx.x;
  if (w >= nwords) return;

  const uint4* p = x4 + (size_t)w * 8;  // 8 x uint4 = 32 floats = one word

  uint32_t nat = 0;
#pragma unroll
  for (int k = 0; k < 8; ++k) {
    uint4 v = p[k];
    nat |= (v.x >> 31) << (4 * k + 0);
    nat |= (v.y >> 31) << (4 * k + 1);
    nat |= (v.z >> 31) << (4 * k + 2);
    nat |= (v.w >> 31) << (4 * k + 3);
  }

  out[w] = __builtin_bswap32(__brev(nat));
}

extern "C" void kernel_launch(void* const* d_in, const int* in_sizes, int n_in,
                              void* d_out, int out_size, void* d_ws, size_t ws_size,
                              hipStream_t stream) {
  const uint4* x4 = (const uint4*)d_in[0];
  uint32_t* out = (uint32_t*)d_out;
  int n = in_sizes[0];       // 2^27, multiple of 32
  int nwords = n / 32;       // == out_size

  const int threads = 256;
  int blocks = (nwords + threads - 1) / threads;
  PackBits_61289183314094_kernel<<<blocks, threads, 0, stream>>>(x4, out, nwords);
}

// Round 2
// 652.059 us; speedup vs baseline: 1.0354x; 1.0354x over previous
//
#include <hip/hip_runtime.h>
#include <stdint.h>

// PackBits: out[w] = packed sign bits of x[32w .. 32w+31].
// Bit mapping (np.packbits MSB-first + little-endian uint32 view):
//   element p -> bit q = 8*(p>>3) + 7 - (p&7)
// Natural-order word nat (bit p = signbit(x[32w+p])) then
//   out = bswap(brev(nat))   — verified correct in R1 (absmax 0).
//
// R2 layout change: lane i loads uint4 at base+i (16 B/lane, per-instruction
// coalesced — R1's 128 B/thread-contiguous pattern scattered each load over
// 64 cache lines and ran at ~0.8 TB/s). Each lane packs a 4-bit sign nibble;
// an 8-lane shfl_xor OR-butterfly assembles the 32-bit word; one lane per
// group stores.

__global__ __launch_bounds__(256) void PackBits_61289183314094_kernel(
    const uint4* __restrict__ x4, uint32_t* __restrict__ out, int n4) {
  int gid = blockIdx.x * blockDim.x + threadIdx.x;  // uint4 index
  if (gid >= n4) return;

  uint4 v = x4[gid];

  int lane = threadIdx.x & 63;
  // nibble: bit j = signbit of float j (natural order within the nibble)
  uint32_t nib = (v.x >> 31) | ((v.y >> 31) << 1) | ((v.z >> 31) << 2) |
                 ((v.w >> 31) << 3);
  // place nibble at its slot within the word owned by this 8-lane group
  uint32_t part = nib << (4 * (lane & 7));
  // OR-butterfly across the 8-lane group
  part |= __shfl_xor(part, 1);
  part |= __shfl_xor(part, 2);
  part |= __shfl_xor(part, 4);

  if ((lane & 7) == 0) {
    out[gid >> 3] = __builtin_bswap32(__brev(part));
  }
}

extern "C" void kernel_launch(void* const* d_in, const int* in_sizes, int n_in,
                              void* d_out, int out_size, void* d_ws, size_t ws_size,
                              hipStream_t stream) {
  const uint4* x4 = (const uint4*)d_in[0];
  uint32_t* out = (uint32_t*)d_out;
  int n = in_sizes[0];   // 2^27 floats
  int n4 = n / 4;        // 2^25 uint4 loads, one per thread

  const int threads = 256;
  int blocks = (n4 + threads - 1) / threads;
  PackBits_61289183314094_kernel<<<blocks, threads, 0, stream>>>(x4, out, n4);
}